// Round 10
// baseline (30.213 us; speedup 1.0000x reference)
//
#include <hip/hip_runtime.h>

// Fused YOLO target encoder — single kernel, compose-on-write, 512-thread
// blocks, NON-TEMPORAL output stores (write-once data, bypass L2 allocate).
//   B=64, O=100, A=9 (3 per layer); layers (128,128,3),(64,64,3),(32,32,3)
//   NSLOT = 49152+12288+3072 = 64512 slots per batch
// Output (flat f32): xcyc[B,NSLOT,2] | wh[B,NSLOT,2] | obj[B,NSLOT] | cls[B,NSLOT] | wt[B,NSLOT,2]
//
// Partition: 1024 blocks = 64 batches x 16 sub-chunks; sub-chunk owns slots
// [r*4032,(r+1)*4032) across all five segments -> no cross-block races.
// 512 threads/block -> 8 waves/block, 4 blocks/CU = 32 waves/CU (max).
//
// Schedule per block (all global STORES happen after the last barrier):
//   1. issue iou float4 loads (threads 0..224) immediately; threads 0..99
//      compute per-object records (m_val + per-layer slot bases) -> LDS;
//      all threads init tbl/ignw.
//   2. LDS-only barrier -> scatter: atomicMax(tbl[slot], o) = numpy
//      last-index-wins; atomicOr ignore bitmap via s_base lookup.
//   3. LDS-only barrier -> compose + stream: every output float written
//      exactly once via nontemporal float4 stores, fire-and-forget.

namespace {
constexpr int B = 64;
constexpr int O = 100;
constexpr int A = 9;
constexpr int NSLOT = 64512;
constexpr int SUB = 16;                       // sub-chunks per batch
constexpr int SPS = NSLOT / SUB;              // 4032 slots per sub-chunk
constexpr int T = 512;                        // threads per block
constexpr long long BASE_XCYC = 0;
constexpr long long BASE_WH   = (long long)B * NSLOT * 2;        // 8257536
constexpr long long BASE_OBJ  = BASE_WH * 2;                     // 16515072
constexpr long long BASE_CLS  = BASE_OBJ + (long long)B * NSLOT; // 20643840
constexpr long long BASE_WT   = BASE_CLS + (long long)B * NSLOT; // 24772608
}

// native clang vector type — __builtin_nontemporal_store rejects HIP_vector_type
typedef float floatx4 __attribute__((ext_vector_type(4)));

__device__ __forceinline__ int layer_offset(int l) {
    return l == 0 ? 0 : (l == 1 ? 49152 : 61440);
}

__device__ __forceinline__ void nt_store4(float* p, float a, float b, float c, float d) {
    floatx4 v = {a, b, c, d};
    __builtin_nontemporal_store(v, (floatx4*)p);
}

__global__ __launch_bounds__(T) void encode_fused(
        const int*   __restrict__ matches,
        const float* __restrict__ ious,
        const float* __restrict__ anc0,
        const float* __restrict__ anc1,
        const float* __restrict__ anc2,
        const float* __restrict__ gt_boxes,
        const int*   __restrict__ gt_ids,
        float*       __restrict__ out,
        const int*   __restrict__ in_h_p,
        const int*   __restrict__ in_w_p) {
    __shared__ int      tbl[SPS];          // last match object idx per rel slot (-1)
    __shared__ unsigned ignw[SPS / 32];    // ignore bitmap (126 words)
    __shared__ float    m_val[O][6];       // fx-lx, fy-ly, whx, why, wt, cls
    __shared__ int      s_base[O][3];      // per-object per-layer slot base (-1)

    const int blk = blockIdx.x;
    const int b = blk >> 4;                // batch
    const int r = blk & (SUB - 1);         // sub-chunk
    const int t = threadIdx.x;
    const int lo = r * SPS;
    const int hi = lo + SPS;

    const float in_w = (float)in_w_p[0];
    const float in_h = (float)in_h_p[0];

    // ---- issue iou loads immediately: threads 0..224 each grab 4 contiguous ----
    float4 iou4 = make_float4(0.f, 0.f, 0.f, 0.f);
    if (t < (A * O) / 4)                       // 225 threads, 900 floats
        iou4 = *(const float4*)(ious + (long long)b * (A * O) + 4 * t);

    // ---- init LDS tables ----
    for (int i = t; i < SPS; i += T) tbl[i] = -1;
    if (t < SPS / 32) ignw[t] = 0u;

    // ---- per-object records (threads 0..O-1) ----
    int m_slot_reg = -1;
    if (t < O) {
        int m = matches[b * O + t];                // m in [0,9)
        float4 g = *(const float4*)(gt_boxes + ((long long)b * O + t) * 4);
        float w = g.z - g.x, h = g.w - g.y;
        float gtx = (g.x + w) * 0.5f, gty = (g.y + h) * 0.5f;
        bool valid = !((gtx == -1.0f) && (gty == -1.0f) && (w == 0.0f) && (h == 0.0f));

        int sb_loc[3];
#pragma unroll
        for (int l = 0; l < 3; ++l) {
            int fw = 128 >> l;
            int sb = -1;
            if (valid) {
                float fx = gtx / in_w * (float)fw;
                float fy = gty / in_h * (float)fw;
                int lx = (int)fx, ly = (int)fy;
                int cell = ly * fw + lx;
                if (cell >= 0 && cell < fw * fw)
                    sb = layer_offset(l) + cell * 3;
            }
            sb_loc[l] = sb;
            s_base[t][l] = sb;
        }

        int layer = m / 3;
        float fxr = 0.f, fyr = 0.f, whx = 0.f, why = 0.f, wt = 0.f, cls = 0.f;
        if (sb_loc[layer] >= 0) {
            m_slot_reg = sb_loc[layer] + (m - layer * 3);
            int fw = 128 >> layer;
            float fx = gtx / in_w * (float)fw;
            float fy = gty / in_h * (float)fw;
            int lx = (int)fx, ly = (int)fy;
            const float* anc = (m < 3) ? anc0 : (m < 6) ? anc1 : anc2;
            int al = m % 3;
            whx = logf(fmaxf(w, 1.0f) / anc[al * 2 + 0]);
            why = logf(fmaxf(h, 1.0f) / anc[al * 2 + 1]);
            wt  = 2.0f - w * h / in_w / in_h;
            cls = (float)gt_ids[b * O + t];
            fxr = fx - (float)lx;
            fyr = fy - (float)ly;
        }
        m_val[t][0] = fxr; m_val[t][1] = fyr;
        m_val[t][2] = whx; m_val[t][3] = why;
        m_val[t][4] = wt;  m_val[t][5] = cls;
    }

    __syncthreads();   // LDS init + records visible (no global stores in flight)

    // ---- scatter records into slot table ----
    if (m_slot_reg >= lo && m_slot_reg < hi)
        atomicMax(&tbl[m_slot_reg - lo], t);       // last object index wins
    if (t < (A * O) / 4) {
        const float iou_k[4] = {iou4.x, iou4.y, iou4.z, iou4.w};
#pragma unroll
        for (int k = 0; k < 4; ++k) {
            if (iou_k[k] >= 0.5f) {
                int idx = 4 * t + k;
                int a = idx / O;
                int o = idx - a * O;
                int l = a / 3;
                int sb = s_base[o][l];
                if (sb >= 0) {
                    int s = sb + (a - l * 3);
                    if (s >= lo && s < hi) {
                        int sr = s - lo;
                        atomicOr(&ignw[sr >> 5], 1u << (sr & 31));
                    }
                }
            }
        }
    }

    __syncthreads();   // table ready (still no global stores in flight)

    // ---- single streaming pass: write every output float exactly once ----
    const long long fx_base = ((long long)b * NSLOT + lo) * 2;
    const long long s_base_g = (long long)b * NSLOT + lo;
    float* p_xcyc = out + BASE_XCYC + fx_base;
    float* p_wh   = out + BASE_WH   + fx_base;
    float* p_wt   = out + BASE_WT   + fx_base;
    float* p_obj  = out + BASE_OBJ  + s_base_g;
    float* p_cls  = out + BASE_CLS  + s_base_g;

    // big segments: window i covers rel slots 2i, 2i+1 (2016 windows)
#pragma unroll 2
    for (int i = t; i < SPS * 2 / 4; i += T) {
        int2 pr = *(const int2*)&tbl[2 * i];       // ds_read_b64
        float vx0 = 0.f, vx1 = 0.f, vx2 = 0.f, vx3 = 0.f;
        float vw0 = 0.f, vw1 = 0.f, vw2 = 0.f, vw3 = 0.f;
        float vt0 = 0.f, vt1 = 0.f, vt2 = 0.f, vt3 = 0.f;
        if (pr.x >= 0) {
            vx0 = m_val[pr.x][0]; vx1 = m_val[pr.x][1];
            vw0 = m_val[pr.x][2]; vw1 = m_val[pr.x][3];
            vt0 = m_val[pr.x][4]; vt1 = m_val[pr.x][4];
        }
        if (pr.y >= 0) {
            vx2 = m_val[pr.y][0]; vx3 = m_val[pr.y][1];
            vw2 = m_val[pr.y][2]; vw3 = m_val[pr.y][3];
            vt2 = m_val[pr.y][4]; vt3 = m_val[pr.y][4];
        }
        nt_store4(p_xcyc + 4 * i, vx0, vx1, vx2, vx3);
        nt_store4(p_wh   + 4 * i, vw0, vw1, vw2, vw3);
        nt_store4(p_wt   + 4 * i, vt0, vt1, vt2, vt3);
    }

    // small segments: window i covers rel slots 4i..4i+3 (1008 windows)
#pragma unroll 2
    for (int i = t; i < SPS / 4; i += T) {
        int s0 = 4 * i;
        unsigned igb = (ignw[s0 >> 5] >> (s0 & 31)) & 0xFu;
        int4 mm = *(const int4*)&tbl[s0];          // ds_read_b128
        float vo0 = 0.f, vo1 = 0.f, vo2 = 0.f, vo3 = 0.f;
        float vc0 = 0.f, vc1 = 0.f, vc2 = 0.f, vc3 = 0.f;
        if (mm.x >= 0) { vo0 = 1.f; vc0 = m_val[mm.x][5]; } else if (igb & 1u) vo0 = -1.f;
        if (mm.y >= 0) { vo1 = 1.f; vc1 = m_val[mm.y][5]; } else if (igb & 2u) vo1 = -1.f;
        if (mm.z >= 0) { vo2 = 1.f; vc2 = m_val[mm.z][5]; } else if (igb & 4u) vo2 = -1.f;
        if (mm.w >= 0) { vo3 = 1.f; vc3 = m_val[mm.w][5]; } else if (igb & 8u) vo3 = -1.f;
        nt_store4(p_obj + 4 * i, vo0, vo1, vo2, vo3);
        nt_store4(p_cls + 4 * i, vc0, vc1, vc2, vc3);
    }
}

extern "C" void kernel_launch(void* const* d_in, const int* in_sizes, int n_in,
                              void* d_out, int out_size, void* d_ws, size_t ws_size,
                              hipStream_t stream) {
    const int*   matches  = (const int*)  d_in[0];
    const float* ious     = (const float*)d_in[1];
    // d_in[2..4] = out0/out1/out2 (shape-only, unused)
    const float* anc0     = (const float*)d_in[5];
    const float* anc1     = (const float*)d_in[6];
    const float* anc2     = (const float*)d_in[7];
    const float* gt_boxes = (const float*)d_in[8];
    const int*   gt_ids   = (const int*)  d_in[9];
    const int*   in_h_p   = (const int*)  d_in[10];
    const int*   in_w_p   = (const int*)  d_in[11];
    float* out = (float*)d_out;

    encode_fused<<<B * SUB, T, 0, stream>>>(matches, ious, anc0, anc1, anc2,
                                            gt_boxes, gt_ids, out, in_h_p, in_w_p);
}

// Round 11
// 24.747 us; speedup vs baseline: 1.2208x; 1.2208x over previous
//
#include <hip/hip_runtime.h>

// Fused YOLO target encoder — single kernel, compose-on-write, 512-thread blocks.
// (R7 configuration — best verified: 24.4 µs. nt-store experiment (R9) regressed
// to 30.2 µs and is reverted: L2 write-combining is the drain buffer here.)
//   B=64, O=100, A=9 (3 per layer); layers (128,128,3),(64,64,3),(32,32,3)
//   NSLOT = 49152+12288+3072 = 64512 slots per batch
// Output (flat f32): xcyc[B,NSLOT,2] | wh[B,NSLOT,2] | obj[B,NSLOT] | cls[B,NSLOT] | wt[B,NSLOT,2]
//
// Partition: 1024 blocks = 64 batches x 16 sub-chunks; sub-chunk owns slots
// [r*4032,(r+1)*4032) across all five segments -> no cross-block races.
// 512 threads/block -> 8 waves/block, 4 blocks/CU = 32 waves/CU (max).
//
// Schedule per block (all global STORES happen after the last barrier):
//   1. issue iou float4 loads (threads 0..224) immediately; threads 0..99
//      compute per-object records (m_val + per-layer slot bases) -> LDS;
//      all threads init tbl/ignw.
//   2. LDS-only barrier -> scatter: atomicMax(tbl[slot], o) = numpy
//      last-index-wins; atomicOr ignore bitmap via s_base lookup.
//   3. LDS-only barrier -> compose + stream: every output float written
//      exactly once, fire-and-forget to kernel end (pure-fill behavior).

namespace {
constexpr int B = 64;
constexpr int O = 100;
constexpr int A = 9;
constexpr int NSLOT = 64512;
constexpr int SUB = 16;                       // sub-chunks per batch
constexpr int SPS = NSLOT / SUB;              // 4032 slots per sub-chunk
constexpr int T = 512;                        // threads per block
constexpr long long BASE_XCYC = 0;
constexpr long long BASE_WH   = (long long)B * NSLOT * 2;        // 8257536
constexpr long long BASE_OBJ  = BASE_WH * 2;                     // 16515072
constexpr long long BASE_CLS  = BASE_OBJ + (long long)B * NSLOT; // 20643840
constexpr long long BASE_WT   = BASE_CLS + (long long)B * NSLOT; // 24772608
}

__device__ __forceinline__ int layer_offset(int l) {
    return l == 0 ? 0 : (l == 1 ? 49152 : 61440);
}

__global__ __launch_bounds__(T) void encode_fused(
        const int*   __restrict__ matches,
        const float* __restrict__ ious,
        const float* __restrict__ anc0,
        const float* __restrict__ anc1,
        const float* __restrict__ anc2,
        const float* __restrict__ gt_boxes,
        const int*   __restrict__ gt_ids,
        float*       __restrict__ out,
        const int*   __restrict__ in_h_p,
        const int*   __restrict__ in_w_p) {
    __shared__ int      tbl[SPS];          // last match object idx per rel slot (-1)
    __shared__ unsigned ignw[SPS / 32];    // ignore bitmap (126 words)
    __shared__ float    m_val[O][6];       // fx-lx, fy-ly, whx, why, wt, cls
    __shared__ int      s_base[O][3];      // per-object per-layer slot base (-1)

    const int blk = blockIdx.x;
    const int b = blk >> 4;                // batch
    const int r = blk & (SUB - 1);         // sub-chunk
    const int t = threadIdx.x;
    const int lo = r * SPS;
    const int hi = lo + SPS;

    const float in_w = (float)in_w_p[0];
    const float in_h = (float)in_h_p[0];

    // ---- issue iou loads immediately: threads 0..224 each grab 4 contiguous ----
    float4 iou4 = make_float4(0.f, 0.f, 0.f, 0.f);
    if (t < (A * O) / 4)                       // 225 threads, 900 floats
        iou4 = *(const float4*)(ious + (long long)b * (A * O) + 4 * t);

    // ---- init LDS tables ----
    for (int i = t; i < SPS; i += T) tbl[i] = -1;
    if (t < SPS / 32) ignw[t] = 0u;

    // ---- per-object records (threads 0..O-1) ----
    int m_slot_reg = -1;
    if (t < O) {
        int m = matches[b * O + t];                // m in [0,9)
        float4 g = *(const float4*)(gt_boxes + ((long long)b * O + t) * 4);
        float w = g.z - g.x, h = g.w - g.y;
        float gtx = (g.x + w) * 0.5f, gty = (g.y + h) * 0.5f;
        bool valid = !((gtx == -1.0f) && (gty == -1.0f) && (w == 0.0f) && (h == 0.0f));

        int sb_loc[3];
#pragma unroll
        for (int l = 0; l < 3; ++l) {
            int fw = 128 >> l;
            int sb = -1;
            if (valid) {
                float fx = gtx / in_w * (float)fw;
                float fy = gty / in_h * (float)fw;
                int lx = (int)fx, ly = (int)fy;
                int cell = ly * fw + lx;
                if (cell >= 0 && cell < fw * fw)
                    sb = layer_offset(l) + cell * 3;
            }
            sb_loc[l] = sb;
            s_base[t][l] = sb;
        }

        int layer = m / 3;
        float fxr = 0.f, fyr = 0.f, whx = 0.f, why = 0.f, wt = 0.f, cls = 0.f;
        if (sb_loc[layer] >= 0) {
            m_slot_reg = sb_loc[layer] + (m - layer * 3);
            int fw = 128 >> layer;
            float fx = gtx / in_w * (float)fw;
            float fy = gty / in_h * (float)fw;
            int lx = (int)fx, ly = (int)fy;
            const float* anc = (m < 3) ? anc0 : (m < 6) ? anc1 : anc2;
            int al = m % 3;
            whx = logf(fmaxf(w, 1.0f) / anc[al * 2 + 0]);
            why = logf(fmaxf(h, 1.0f) / anc[al * 2 + 1]);
            wt  = 2.0f - w * h / in_w / in_h;
            cls = (float)gt_ids[b * O + t];
            fxr = fx - (float)lx;
            fyr = fy - (float)ly;
        }
        m_val[t][0] = fxr; m_val[t][1] = fyr;
        m_val[t][2] = whx; m_val[t][3] = why;
        m_val[t][4] = wt;  m_val[t][5] = cls;
    }

    __syncthreads();   // LDS init + records visible (no global stores in flight)

    // ---- scatter records into slot table ----
    if (m_slot_reg >= lo && m_slot_reg < hi)
        atomicMax(&tbl[m_slot_reg - lo], t);       // last object index wins
    if (t < (A * O) / 4) {
        const float iou_k[4] = {iou4.x, iou4.y, iou4.z, iou4.w};
#pragma unroll
        for (int k = 0; k < 4; ++k) {
            if (iou_k[k] >= 0.5f) {
                int idx = 4 * t + k;
                int a = idx / O;
                int o = idx - a * O;
                int l = a / 3;
                int sb = s_base[o][l];
                if (sb >= 0) {
                    int s = sb + (a - l * 3);
                    if (s >= lo && s < hi) {
                        int sr = s - lo;
                        atomicOr(&ignw[sr >> 5], 1u << (sr & 31));
                    }
                }
            }
        }
    }

    __syncthreads();   // table ready (still no global stores in flight)

    // ---- single streaming pass: write every output float exactly once ----
    const long long fx_base = ((long long)b * NSLOT + lo) * 2;
    const long long s_base_g = (long long)b * NSLOT + lo;
    float4* p_xcyc = (float4*)(out + BASE_XCYC + fx_base);
    float4* p_wh   = (float4*)(out + BASE_WH   + fx_base);
    float4* p_wt   = (float4*)(out + BASE_WT   + fx_base);
    float4* p_obj  = (float4*)(out + BASE_OBJ  + s_base_g);
    float4* p_cls  = (float4*)(out + BASE_CLS  + s_base_g);
    const float4 z = make_float4(0.f, 0.f, 0.f, 0.f);

    // big segments: window i covers rel slots 2i, 2i+1 (2016 windows)
#pragma unroll 2
    for (int i = t; i < SPS * 2 / 4; i += T) {
        int2 pr = *(const int2*)&tbl[2 * i];       // ds_read_b64
        float4 vx = z, vw = z, vt = z;
        if (pr.x >= 0) {
            vx.x = m_val[pr.x][0]; vx.y = m_val[pr.x][1];
            vw.x = m_val[pr.x][2]; vw.y = m_val[pr.x][3];
            vt.x = m_val[pr.x][4]; vt.y = m_val[pr.x][4];
        }
        if (pr.y >= 0) {
            vx.z = m_val[pr.y][0]; vx.w = m_val[pr.y][1];
            vw.z = m_val[pr.y][2]; vw.w = m_val[pr.y][3];
            vt.z = m_val[pr.y][4]; vt.w = m_val[pr.y][4];
        }
        p_xcyc[i] = vx;
        p_wh[i]   = vw;
        p_wt[i]   = vt;
    }

    // small segments: window i covers rel slots 4i..4i+3 (1008 windows)
#pragma unroll 2
    for (int i = t; i < SPS / 4; i += T) {
        int s0 = 4 * i;
        unsigned igb = (ignw[s0 >> 5] >> (s0 & 31)) & 0xFu;
        int4 mm = *(const int4*)&tbl[s0];          // ds_read_b128
        float4 vo = z, vc = z;
        if (mm.x >= 0) { vo.x = 1.f; vc.x = m_val[mm.x][5]; } else if (igb & 1u) vo.x = -1.f;
        if (mm.y >= 0) { vo.y = 1.f; vc.y = m_val[mm.y][5]; } else if (igb & 2u) vo.y = -1.f;
        if (mm.z >= 0) { vo.z = 1.f; vc.z = m_val[mm.z][5]; } else if (igb & 4u) vo.z = -1.f;
        if (mm.w >= 0) { vo.w = 1.f; vc.w = m_val[mm.w][5]; } else if (igb & 8u) vo.w = -1.f;
        p_obj[i] = vo;
        p_cls[i] = vc;
    }
}

extern "C" void kernel_launch(void* const* d_in, const int* in_sizes, int n_in,
                              void* d_out, int out_size, void* d_ws, size_t ws_size,
                              hipStream_t stream) {
    const int*   matches  = (const int*)  d_in[0];
    const float* ious     = (const float*)d_in[1];
    // d_in[2..4] = out0/out1/out2 (shape-only, unused)
    const float* anc0     = (const float*)d_in[5];
    const float* anc1     = (const float*)d_in[6];
    const float* anc2     = (const float*)d_in[7];
    const float* gt_boxes = (const float*)d_in[8];
    const int*   gt_ids   = (const int*)  d_in[9];
    const int*   in_h_p   = (const int*)  d_in[10];
    const int*   in_w_p   = (const int*)  d_in[11];
    float* out = (float*)d_out;

    encode_fused<<<B * SUB, T, 0, stream>>>(matches, ious, anc0, anc1, anc2,
                                            gt_boxes, gt_ids, out, in_h_p, in_w_p);
}